// Round 1
// baseline (67191.168 us; speedup 1.0000x reference)
//
#include <hip/hip_runtime.h>

#define NMOL 256
#define MOLS 48
#define NATOMS 12288           // NMOL*MOLS
#define NORB 192               // 4*MOLS
#define PPM 1128               // pairs per molecule = 48*47/2
#define NPAIR 288768           // NMOL*PPM
#define MATSZ 36864            // NORB*NORB
#define EVC 27.21f

// output offsets (floats)
#define F_OFF   0
#define E_OFF   9437184
#define P_OFF   9486336
#define H_OFF   18923520
#define WMAT_OFF 28360704
#define CHG_OFF 57237504
#define NCV_OFF 57249792

__device__ __forceinline__ int pairoff(int i, int j) {
    // index of (i<j) in row-major triu(k=1) enumeration of 48x48
    return 47 * i - (i * (i - 1)) / 2 + (j - i - 1);
}

// ---------------- per-pair: w_ss + Hcore off-diagonal blocks ----------------
__global__ void pair_kernel(
    const int* __restrict__ idxi, const int* __restrict__ idxj,
    const float* __restrict__ xij, const float* __restrict__ rij,
    const float* __restrict__ zeta_s, const float* __restrict__ zeta_p,
    const float* __restrict__ g_ss,
    const float* __restrict__ beta_s, const float* __restrict__ beta_p,
    float* __restrict__ wss, float* __restrict__ H)
{
    int pp = blockIdx.x * blockDim.x + threadIdx.x;
    if (pp >= NPAIR) return;
    int i = idxi[pp], j = idxj[pp];
    float r = rij[pp];
    float rho = 7.0f / g_ss[i] + 7.0f / g_ss[j];
    float base = 1.0f / sqrtf(r * r + rho * rho);
    float wv = EVC * base;
    wss[pp] = wv;

    float x[3] = { xij[pp * 3 + 0], xij[pp * 3 + 1], xij[pp * 3 + 2] };
    float zsi = zeta_s[i], zpi = zeta_p[i], zsj = zeta_s[j], zpj = zeta_p[j];
    float e_ss = expf(-0.5f * (zsi + zsj) * r);
    float e_sp = expf(-0.5f * (zsi + zpj) * r);
    float e_ps = expf(-0.5f * (zpi + zsj) * r);
    float e_pp = expf(-0.5f * (zpi + zpj) * r);

    float S[4][4];
    S[0][0] = e_ss;
    #pragma unroll
    for (int k = 0; k < 3; ++k) {
        S[0][1 + k] = x[k] * e_sp;
        S[1 + k][0] = -x[k] * e_ps;
        #pragma unroll
        for (int l = 0; l < 3; ++l)
            S[1 + k][1 + l] = ((k == l ? 1.0f : 0.0f) - x[k] * x[l]) * e_pp;
    }
    float boi[4] = { beta_s[i], beta_p[i], beta_p[i], beta_p[i] };
    float boj[4] = { beta_s[j], beta_p[j], beta_p[j], beta_p[j] };

    int mol = i / MOLS, ai = i % MOLS, aj = j % MOLS;
    float* Hm = H + (size_t)mol * MATSZ;
    #pragma unroll
    for (int p = 0; p < 4; ++p)
        #pragma unroll
        for (int q = 0; q < 4; ++q) {
            float v = 0.5f * (boi[p] + boj[q]) * S[p][q];
            Hm[(4 * ai + p) * NORB + 4 * aj + q] = v;
            Hm[(4 * aj + q) * NORB + 4 * ai + p] = v;
        }
}

// ---------------- w output (coalesced) ----------------
__global__ void wout_kernel(const float* __restrict__ wss, float* __restrict__ w_out)
{
    int idx = blockIdx.x * blockDim.x + threadIdx.x;
    if (idx >= NPAIR * 100) return;
    int pp = idx / 100, ab = idx % 100;
    int a = ab / 10, b = ab % 10;
    w_out[idx] = wss[pp] * (1.0f + 0.05f * (float)a) * (1.0f + 0.05f * (float)b);
}

// ---------------- per-atom: vatt gather + Hcore diagonal blocks ----------------
__global__ void atom_kernel(const int* __restrict__ Z,
    const float* __restrict__ U_ss, const float* __restrict__ U_pp,
    const float* __restrict__ wss, float* __restrict__ H)
{
    int a = blockIdx.x * blockDim.x + threadIdx.x;
    if (a >= NATOMS) return;
    int mol = a / MOLS, ai = a % MOLS;
    const float* wm = wss + mol * PPM;
    float vatt = 0.0f;
    for (int j = 0; j < MOLS; ++j) {
        if (j == ai) continue;
        int i_ = ai < j ? ai : j;
        int j_ = ai < j ? j : ai;
        float torej = (float)(Z[mol * MOLS + j] - 2);
        vatt -= torej * wm[pairoff(i_, j_)];
    }
    float u0 = U_ss[a], u1 = U_pp[a];
    float* Hm = H + (size_t)mol * MATSZ;
    #pragma unroll
    for (int p = 0; p < 4; ++p)
        #pragma unroll
        for (int q = 0; q < 4; ++q)
            Hm[(4 * ai + p) * NORB + 4 * ai + q] =
                (p == q) ? ((p == 0 ? u0 : u1) + vatt) : 0.0f;
}

// ---------------- initial density ----------------
__global__ void pinit_kernel(const int* __restrict__ Z, float* __restrict__ P)
{
    int idx = blockIdx.x * blockDim.x + threadIdx.x;
    if (idx >= NMOL * MATSZ) return;
    int mol = idx / MATSZ, rem = idx % MATSZ;
    int r = rem / NORB, c = rem % NORB;
    float v = 0.0f;
    if (r == c) v = (float)(Z[mol * MOLS + r / 4] - 2) * 0.25f;
    P[idx] = v;
}

// ---------------- Ptot (trace of diagonal density block) ----------------
__global__ void ptot_kernel(const float* __restrict__ P, float* __restrict__ Ptot)
{
    int a = blockIdx.x * blockDim.x + threadIdx.x;
    if (a >= NATOMS) return;
    int mol = a / MOLS, ai = a % MOLS;
    const float* Pm = P + (size_t)mol * MATSZ;
    float t = 0.0f;
    #pragma unroll
    for (int p = 0; p < 4; ++p) t += Pm[(4 * ai + p) * NORB + 4 * ai + p];
    Ptot[a] = t;
}

// ---------------- Fock diagonal blocks ----------------
__global__ void fockdiag_kernel(
    const float* __restrict__ P, const float* __restrict__ H, float* __restrict__ F,
    const float* __restrict__ Ptot, const float* __restrict__ wss,
    const float* __restrict__ g_ss, const float* __restrict__ g_sp,
    const float* __restrict__ g_pp, const float* __restrict__ g_p2,
    const float* __restrict__ h_sp)
{
    int a = blockIdx.x * blockDim.x + threadIdx.x;
    if (a >= NATOMS) return;
    int mol = a / MOLS, ai = a % MOLS;
    const float* wm = wss + mol * PPM;
    const float* ptm = Ptot + mol * MOLS;
    float vc = 0.0f;
    for (int j = 0; j < MOLS; ++j) {
        if (j == ai) continue;
        int i_ = ai < j ? ai : j;
        int j_ = ai < j ? j : ai;
        vc += wm[pairoff(i_, j_)] * ptm[j];
    }
    const float* Pm = P + (size_t)mol * MATSZ;
    float Pd[4][4];
    #pragma unroll
    for (int p = 0; p < 4; ++p)
        #pragma unroll
        for (int q = 0; q < 4; ++q)
            Pd[p][q] = Pm[(4 * ai + p) * NORB + 4 * ai + q];

    float Pss = Pd[0][0];
    float Pp0 = Pd[1][1], Pp1 = Pd[2][2], Pp2 = Pd[3][3];
    float Ppp = Pp0 + Pp1 + Pp2;
    float gss = g_ss[a], gsp = g_sp[a], gpp = g_pp[a], gp2 = g_p2[a], hsp = h_sp[a];
    float csp = 1.5f * hsp - 0.5f * gsp;
    float gsp_h = gsp - 0.5f * hsp;
    float fss = 0.5f * Pss * gss + Ppp * gsp_h;
    float cp = 1.25f * gp2 - 0.25f * gpp;
    float fpp0 = Pss * gsp_h + 0.5f * Pp0 * gpp + (Ppp - Pp0) * cp;
    float fpp1 = Pss * gsp_h + 0.5f * Pp1 * gpp + (Ppp - Pp1) * cp;
    float fpp2 = Pss * gsp_h + 0.5f * Pp2 * gpp + (Ppp - Pp2) * cp;
    float coff = 0.75f * gpp - 1.25f * gp2;

    float Fd[4][4];
    Fd[0][0] = fss + vc;
    Fd[1][1] = fpp0 + vc; Fd[2][2] = fpp1 + vc; Fd[3][3] = fpp2 + vc;
    #pragma unroll
    for (int k = 0; k < 3; ++k) {
        Fd[0][1 + k] = Pd[0][1 + k] * csp;
        Fd[1 + k][0] = Pd[1 + k][0] * csp;
    }
    Fd[1][2] = coff * Pd[1][2]; Fd[1][3] = coff * Pd[1][3];
    Fd[2][1] = coff * Pd[2][1]; Fd[2][3] = coff * Pd[2][3];
    Fd[3][1] = coff * Pd[3][1]; Fd[3][2] = coff * Pd[3][2];

    const float* Hm = H + (size_t)mol * MATSZ;
    float* Fm = F + (size_t)mol * MATSZ;
    #pragma unroll
    for (int p = 0; p < 4; ++p)
        #pragma unroll
        for (int q = 0; q < 4; ++q) {
            int ix = (4 * ai + p) * NORB + 4 * ai + q;
            Fm[ix] = Hm[ix] + Fd[p][q];
        }
}

// ---------------- Fock off-diagonal blocks ----------------
__global__ void fockoff_kernel(const int* __restrict__ idxi, const int* __restrict__ idxj,
    const float* __restrict__ P, const float* __restrict__ H, float* __restrict__ F,
    const float* __restrict__ wss)
{
    int pp = blockIdx.x * blockDim.x + threadIdx.x;
    if (pp >= NPAIR) return;
    int i = idxi[pp], j = idxj[pp];
    int mol = i / MOLS, ai = i % MOLS, aj = j % MOLS;
    float wv = wss[pp];
    const float* Pm = P + (size_t)mol * MATSZ;
    const float* Hm = H + (size_t)mol * MATSZ;
    float* Fm = F + (size_t)mol * MATSZ;
    #pragma unroll
    for (int p = 0; p < 4; ++p)
        #pragma unroll
        for (int q = 0; q < 4; ++q) {
            int ij = (4 * ai + p) * NORB + 4 * aj + q;
            int ji = (4 * aj + q) * NORB + 4 * ai + p;
            float f = -0.5f * wv * Pm[ij];
            Fm[ij] = Hm[ij] + f;
            Fm[ji] = Hm[ji] + f;
        }
}

// ---------------- batched eigensolver: one-sided Jacobi on sigma*I - F ----------------
#define EIG_T 768
#define ESTR 196     // padded column stride in floats
#define ESTR4 49     // in float4
#define EIG_LDS (( (ESTR*NORB) + 2*NORB ) * 4 + NORB * 4)   // B + colv + colv2 + slot

__global__ void __launch_bounds__(EIG_T)
eigh_kernel(const float* __restrict__ Fg, const int* __restrict__ noccA,
            float* __restrict__ Wout, float* __restrict__ eout, int mode)
{
    extern __shared__ float sm[];
    float* B = sm;                          // ESTR*NORB
    float* colv = sm + ESTR * NORB;         // NORB
    float* colv2 = colv + NORB;             // NORB
    int* slot = (int*)(colv2 + NORB);       // NORB
    __shared__ int nrot;
    __shared__ float sigma;

    const int mol = blockIdx.x;
    const int tid = threadIdx.x;
    const float* Fm = Fg + (size_t)mol * MATSZ;

    // load F (symmetric: col-major == row-major), padded columns
    for (int i4 = tid; i4 < NORB * 48; i4 += EIG_T) {
        int c = i4 / 48, r4 = i4 % 48;
        float4 v = ((const float4*)Fm)[i4];
        ((float4*)B)[c * ESTR4 + r4] = v;
    }
    __syncthreads();

    // Gershgorin upper bound per column (4 threads/col)
    {
        int c = tid >> 2, part = tid & 3;
        const float4* col = (const float4*)B + c * ESTR4 + part * 12;
        float s = 0.0f;
        #pragma unroll
        for (int u = 0; u < 12; ++u) {
            float4 v = col[u];
            s += fabsf(v.x) + fabsf(v.y) + fabsf(v.z) + fabsf(v.w);
        }
        s += __shfl_xor(s, 1); s += __shfl_xor(s, 2);
        if (part == 0) { float d = B[c * ESTR + c]; colv[c] = s - fabsf(d) + d; }
    }
    __syncthreads();
    if (tid == 0) {
        float m = -3.4e38f;
        for (int i = 0; i < NORB; ++i) m = fmaxf(m, colv[i]);
        sigma = m + 1.0f + 1e-3f * fabsf(m);
    }
    __syncthreads();
    float sg = sigma;

    // B = sigma*I - F
    for (int i4 = tid; i4 < NORB * 48; i4 += EIG_T) {
        int c = i4 / 48, r4 = i4 % 48;
        float4* pv = (float4*)B + c * ESTR4 + r4;
        float4 v = *pv;
        v.x = -v.x; v.y = -v.y; v.z = -v.z; v.w = -v.w;
        *pv = v;
    }
    __syncthreads();
    if (tid < NORB) B[tid * ESTR + tid] += sg;
    __syncthreads();

    // one-sided Jacobi sweeps (tournament ordering, 96 disjoint pairs/round)
    const int team = tid >> 3, lane = tid & 7;
    const float tol2 = 2.5e-11f;   // (5e-6 relative)^2
    for (int sweep = 0; sweep < 14; ++sweep) {
        if (tid == 0) nrot = 0;
        __syncthreads();
        for (int r = 0; r < NORB - 1; ++r) {
            int p, q;
            if (team == 0) { p = NORB - 1; q = r; }
            else {
                p = (r + team) % (NORB - 1);
                q = (r - team + (NORB - 1)) % (NORB - 1);
            }
            float4* bp = (float4*)B + p * ESTR4 + lane * 6;
            float4* bq = (float4*)B + q * ESTR4 + lane * 6;
            float4 xp[6], xq[6];
            #pragma unroll
            for (int u = 0; u < 6; ++u) { xp[u] = bp[u]; xq[u] = bq[u]; }
            float app = 0.f, aqq = 0.f, apq = 0.f;
            #pragma unroll
            for (int u = 0; u < 6; ++u) {
                app += xp[u].x * xp[u].x + xp[u].y * xp[u].y + xp[u].z * xp[u].z + xp[u].w * xp[u].w;
                aqq += xq[u].x * xq[u].x + xq[u].y * xq[u].y + xq[u].z * xq[u].z + xq[u].w * xq[u].w;
                apq += xp[u].x * xq[u].x + xp[u].y * xq[u].y + xp[u].z * xq[u].z + xp[u].w * xq[u].w;
            }
            app += __shfl_xor(app, 1); app += __shfl_xor(app, 2); app += __shfl_xor(app, 4);
            aqq += __shfl_xor(aqq, 1); aqq += __shfl_xor(aqq, 2); aqq += __shfl_xor(aqq, 4);
            apq += __shfl_xor(apq, 1); apq += __shfl_xor(apq, 2); apq += __shfl_xor(apq, 4);
            if (apq * apq > tol2 * app * aqq) {
                float zeta = (aqq - app) / (2.0f * apq);
                float t = copysignf(1.0f, zeta) / (fabsf(zeta) + sqrtf(1.0f + zeta * zeta));
                float cc = 1.0f / sqrtf(1.0f + t * t);
                float ss = t * cc;
                #pragma unroll
                for (int u = 0; u < 6; ++u) {
                    float4 av = xp[u], bv = xq[u], na, nb;
                    na.x = cc * av.x - ss * bv.x;  nb.x = ss * av.x + cc * bv.x;
                    na.y = cc * av.y - ss * bv.y;  nb.y = ss * av.y + cc * bv.y;
                    na.z = cc * av.z - ss * bv.z;  nb.z = ss * av.z + cc * bv.z;
                    na.w = cc * av.w - ss * bv.w;  nb.w = ss * av.w + cc * bv.w;
                    bp[u] = na; bq[u] = nb;
                }
                if (lane == 0) atomicAdd(&nrot, 1);
            }
            __syncthreads();
        }
        int done = (nrot == 0);
        __syncthreads();
        if (done) break;
    }

    // column norms^2
    {
        int c = tid >> 2, part = tid & 3;
        const float4* col = (const float4*)B + c * ESTR4 + part * 12;
        float s = 0.0f;
        #pragma unroll
        for (int u = 0; u < 12; ++u) {
            float4 v = col[u];
            s += v.x * v.x + v.y * v.y + v.z * v.z + v.w * v.w;
        }
        s += __shfl_xor(s, 1); s += __shfl_xor(s, 2);
        if (part == 0) colv[c] = s;
    }
    __syncthreads();

    if (mode == 0) {
        // occupied = nocc largest norms (= smallest eigenvalues of F)
        int noccm = noccA[mol];
        if (tid < NORB) {
            float nc = colv[tid];
            int rank = 0;
            for (int j2 = 0; j2 < NORB; ++j2) {
                float nj = colv[j2];
                rank += (nj > nc) || (nj == nc && j2 < tid);
            }
            slot[tid] = rank;
            colv2[tid] = 1.41421356f / sqrtf(nc);   // sqrt(2)/||b||
        }
        __syncthreads();
        float* Wm = Wout + (size_t)mol * MATSZ;
        for (int i4 = tid; i4 < NORB * 48; i4 += EIG_T) {
            int c = i4 / 48, r4 = i4 % 48;
            int sl = slot[c];
            if (sl < noccm) {
                float scl = colv2[c];
                float4 v = ((float4*)B)[c * ESTR4 + r4];
                float4 o;
                o.x = v.x * scl; o.y = v.y * scl; o.z = v.z * scl; o.w = v.w * scl;
                ((float4*)Wm)[sl * 48 + r4] = o;
            }
        }
    } else {
        // eigenvalues ascending
        if (tid < NORB) colv2[tid] = sg - sqrtf(colv[tid]);
        __syncthreads();
        if (tid < NORB) {
            float ec = colv2[tid];
            int rank = 0;
            for (int j2 = 0; j2 < NORB; ++j2) {
                float ej = colv2[j2];
                rank += (ej < ec) || (ej == ec && j2 < tid);
            }
            eout[mol * NORB + rank] = ec;
        }
    }
}

// ---------------- Pnew = W^T W, mix, err ----------------
__global__ void __launch_bounds__(256)
pmix_kernel(const float* __restrict__ W, const int* __restrict__ noccA,
            float* __restrict__ P, unsigned int* __restrict__ err, int last)
{
    int mol = blockIdx.x / 36;
    int tile = blockIdx.x % 36;
    int i0 = (tile / 6) * 32, j0 = (tile % 6) * 32;
    int K = noccA[mol];
    const float* Wm = W + (size_t)mol * MATSZ;
    __shared__ float As[32][33];
    __shared__ float Bs[32][33];
    int t = threadIdx.x;
    int ty = t >> 4, tx = t & 15;
    float acc00 = 0.f, acc01 = 0.f, acc10 = 0.f, acc11 = 0.f;
    for (int k0 = 0; k0 < K; k0 += 32) {
        for (int l = t; l < 1024; l += 256) {
            int k = l >> 5, idx = l & 31;
            bool ok = (k0 + k) < K;
            As[k][idx] = ok ? Wm[(k0 + k) * NORB + i0 + idx] : 0.0f;
            Bs[k][idx] = ok ? Wm[(k0 + k) * NORB + j0 + idx] : 0.0f;
        }
        __syncthreads();
        #pragma unroll 8
        for (int k = 0; k < 32; ++k) {
            float a0 = As[k][2 * ty], a1 = As[k][2 * ty + 1];
            float b0 = Bs[k][2 * tx], b1 = Bs[k][2 * tx + 1];
            acc00 += a0 * b0; acc01 += a0 * b1; acc10 += a1 * b0; acc11 += a1 * b1;
        }
        __syncthreads();
    }
    float* Pm = P + (size_t)mol * MATSZ;
    float lmax = 0.0f;
    int ib = i0 + 2 * ty, jb = j0 + 2 * tx;
    {
        float po, pn;
        po = Pm[ib * NORB + jb];           pn = acc00; lmax = fmaxf(lmax, fabsf(pn - po)); Pm[ib * NORB + jb] = 0.5f * (po + pn);
        po = Pm[ib * NORB + jb + 1];       pn = acc01; lmax = fmaxf(lmax, fabsf(pn - po)); Pm[ib * NORB + jb + 1] = 0.5f * (po + pn);
        po = Pm[(ib + 1) * NORB + jb];     pn = acc10; lmax = fmaxf(lmax, fabsf(pn - po)); Pm[(ib + 1) * NORB + jb] = 0.5f * (po + pn);
        po = Pm[(ib + 1) * NORB + jb + 1]; pn = acc11; lmax = fmaxf(lmax, fabsf(pn - po)); Pm[(ib + 1) * NORB + jb + 1] = 0.5f * (po + pn);
    }
    if (last) {
        #pragma unroll
        for (int o = 32; o >= 1; o >>= 1) lmax = fmaxf(lmax, __shfl_xor(lmax, o));
        __shared__ float wm4[4];
        if ((t & 63) == 0) wm4[t >> 6] = lmax;
        __syncthreads();
        if (t == 0) {
            float m = fmaxf(fmaxf(wm4[0], wm4[1]), fmaxf(wm4[2], wm4[3]));
            atomicMax(err + mol, __float_as_uint(m));
        }
    }
}

// ---------------- charge + notconverged ----------------
__global__ void finish_kernel(const int* __restrict__ Z, const float* __restrict__ P,
    const float* __restrict__ errf, float* __restrict__ chg, float* __restrict__ ncv)
{
    int a = blockIdx.x * blockDim.x + threadIdx.x;
    if (a < NATOMS) {
        int mol = a / MOLS, ai = a % MOLS;
        const float* Pm = P + (size_t)mol * MATSZ;
        float tr = 0.0f;
        #pragma unroll
        for (int p = 0; p < 4; ++p) tr += Pm[(4 * ai + p) * NORB + 4 * ai + p];
        chg[a] = (float)(Z[a] - 2) - tr;
    }
    if (a < NMOL) ncv[a] = (errf[a] > 1e-6f) ? 1.0f : 0.0f;
}

extern "C" void kernel_launch(void* const* d_in, const int* in_sizes, int n_in,
                              void* d_out, int out_size, void* d_ws, size_t ws_size,
                              hipStream_t stream)
{
    (void)in_sizes; (void)n_in; (void)out_size; (void)ws_size;

    const int*   nocc   = (const int*)d_in[3];
    const int*   Z      = (const int*)d_in[4];
    const int*   idxi   = (const int*)d_in[9];
    const int*   idxj   = (const int*)d_in[10];
    const float* xij    = (const float*)d_in[13];
    const float* rij    = (const float*)d_in[14];
    const float* zeta_s = (const float*)d_in[15];
    const float* zeta_p = (const float*)d_in[16];
    const float* U_ss   = (const float*)d_in[17];
    const float* U_pp   = (const float*)d_in[18];
    const float* g_ss   = (const float*)d_in[19];
    const float* g_sp   = (const float*)d_in[20];
    const float* g_pp   = (const float*)d_in[21];
    const float* g_p2   = (const float*)d_in[22];
    const float* h_sp   = (const float*)d_in[23];
    const float* beta_s = (const float*)d_in[24];
    const float* beta_p = (const float*)d_in[25];

    float* out     = (float*)d_out;
    float* F_out   = out + F_OFF;
    float* e_out   = out + E_OFF;
    float* P_out   = out + P_OFF;
    float* H_out   = out + H_OFF;
    float* w_out   = out + WMAT_OFF;
    float* chg_out = out + CHG_OFF;
    float* ncv_out = out + NCV_OFF;

    char* wsb = (char*)d_ws;
    float* Wocc = (float*)wsb;                                  // 37,748,736 B
    float* wss  = (float*)(wsb + 37748736);                     //  1,155,072 B
    float* Ptot = (float*)(wsb + 37748736 + 1155072);           //     49,152 B
    unsigned int* err = (unsigned int*)(wsb + 37748736 + 1155072 + 49152); // 1 KB

    hipMemsetAsync(err, 0, NMOL * sizeof(unsigned int), stream);

    hipFuncSetAttribute(reinterpret_cast<const void*>(eigh_kernel),
                        hipFuncAttributeMaxDynamicSharedMemorySize, EIG_LDS);

    pair_kernel<<<NPAIR / 256, 256, 0, stream>>>(idxi, idxj, xij, rij, zeta_s, zeta_p,
                                                 g_ss, beta_s, beta_p, wss, H_out);
    wout_kernel<<<(NPAIR * 100) / 256, 256, 0, stream>>>(wss, w_out);
    atom_kernel<<<NATOMS / 256, 256, 0, stream>>>(Z, U_ss, U_pp, wss, H_out);
    pinit_kernel<<<(NMOL * MATSZ) / 256, 256, 0, stream>>>(Z, P_out);

    for (int it = 0; it < 9; ++it) {
        ptot_kernel<<<NATOMS / 256, 256, 0, stream>>>(P_out, Ptot);
        fockdiag_kernel<<<NATOMS / 256, 256, 0, stream>>>(P_out, H_out, F_out, Ptot, wss,
                                                          g_ss, g_sp, g_pp, g_p2, h_sp);
        fockoff_kernel<<<NPAIR / 256, 256, 0, stream>>>(idxi, idxj, P_out, H_out, F_out, wss);
        if (it < 8) {
            eigh_kernel<<<NMOL, EIG_T, EIG_LDS, stream>>>(F_out, nocc, Wocc, e_out, 0);
            pmix_kernel<<<NMOL * 36, 256, 0, stream>>>(Wocc, nocc, P_out, err, (it == 7) ? 1 : 0);
        } else {
            eigh_kernel<<<NMOL, EIG_T, EIG_LDS, stream>>>(F_out, nocc, Wocc, e_out, 1);
        }
    }
    finish_kernel<<<NATOMS / 256, 256, 0, stream>>>(Z, P_out, (const float*)err, chg_out, ncv_out);
}